// Round 6
// baseline (48.484 us; speedup 1.0000x reference)
//
#include <hip/hip_runtime.h>

// NgramMinPooling: B=32, S=2048, H=512, N_GRAM=3, float32.
// Row r selected (r in sorted+unique rand_index):
//   m = min(x[r], x[r-1], x[r-2])  (within batch; rows shifted past the
//   batch start contribute 0 -- reference zero-pads)
// else m = x[r].
// out = sigmoid(x)*m + (1-sigmoid(x))*x
//
// SINGLE fused kernel (round-5 removed the build_flags dispatch):
//  - 1024 threads = 8 rows/block, one float4 per thread per row
//  - bulk row loads issued FIRST (v1/v2 unconditional: same-block rows are
//    L1 hits, selection only gates the final select -> search latency is
//    off the critical path)
//  - membership via 2-level parallel search of the sorted idx array:
//    wave 0 probes at stride ceil(n/64) + __ballot -> window; all 1024
//    threads scan the <=726-entry window coalesced -> LDS sel[8].
//    Dependent-load depth 2 (vs 17 for per-block binary search, round 1).
//  - XCD-contiguous block swizzle: boundary neighbor reads hit same-XCD L2
//  - nontemporal stores: out is write-once, keep it out of L2

#define S_LEN 2048
#define H_LEN 512
#define ROWS_PER_BLOCK 8
#define NTHREADS 1024

typedef float f32x4 __attribute__((ext_vector_type(4)));

__global__ __launch_bounds__(NTHREADS)
void ngram_min_pool(const float* __restrict__ x,
                    const int* __restrict__ idx,
                    int n_idx,
                    float* __restrict__ out,
                    int nwg)
{
    __shared__ int s_k;
    __shared__ unsigned char s_sel[ROWS_PER_BLOCK];

    // XCD-contiguous swizzle: XCD j owns blocks [j*nwg/8, (j+1)*nwg/8)
    int bid = blockIdx.x;
    const int cpx = nwg >> 3;               // nwg % 8 == 0 (8192)
    bid = (bid & 7) * cpx + (bid >> 3);

    const int tid  = threadIdx.x;
    const int rowg = tid >> 7;              // which of the 8 rows
    const int row  = bid * ROWS_PER_BLOCK + rowg;
    const int lane = tid & 127;             // float4 slot within the row
    const int s    = row & (S_LEN - 1);     // position within sequence

    // ---- bulk loads first: 16 KB/block, hides the search latency ----
    const size_t base = (size_t)row * H_LEN;
    const f32x4 v0 = reinterpret_cast<const f32x4*>(x + base)[lane];
    f32x4 v1 = (f32x4)(0.f);
    f32x4 v2 = (f32x4)(0.f);
    if (s >= 1) v1 = reinterpret_cast<const f32x4*>(x + base - H_LEN)[lane];
    if (s >= 2) v2 = reinterpret_cast<const f32x4*>(x + base - 2 * H_LEN)[lane];

    // ---- 2-level membership search for rows [R, R+8) ----
    const int R = bid * ROWS_PER_BLOCK;
    const int stride1 = (n_idx + 63) >> 6;  // 717 for n=45875
    if (tid < ROWS_PER_BLOCK) s_sel[tid] = 0;
    if (tid < 64) {                          // wave 0 only
        int p = tid * stride1;
        if (p > n_idx - 1) p = n_idx - 1;
        const bool pred = idx[p] < R;
        const unsigned long long b = __ballot(pred);
        if (tid == 0) s_k = __popcll(b);
    }
    __syncthreads();
    const int k  = s_k;                      // # strided probes < R
    const int w0 = (k == 0) ? 0 : (k - 1) * stride1 + 1;
    const int we = min(w0 + stride1 + 9, n_idx);
    for (int p = w0 + tid; p < we; p += NTHREADS) {   // one iter for n=45875
        const unsigned d = (unsigned)(idx[p] - R);
        if (d < ROWS_PER_BLOCK) s_sel[d] = 1;         // idx unique: no race
    }
    __syncthreads();
    const bool selected = s_sel[rowg] != 0;  // wave-uniform (128 thr/row)

    // ---- min + select + sigmoid blend ----
    f32x4 m;
    m.x = fminf(v0.x, fminf(v1.x, v2.x));
    m.y = fminf(v0.y, fminf(v1.y, v2.y));
    m.z = fminf(v0.z, fminf(v1.z, v2.z));
    m.w = fminf(v0.w, fminf(v1.w, v2.w));
    if (!selected) m = v0;

    f32x4 r;
    const float gx = 1.0f / (1.0f + __expf(-v0.x));
    const float gy = 1.0f / (1.0f + __expf(-v0.y));
    const float gz = 1.0f / (1.0f + __expf(-v0.z));
    const float gw = 1.0f / (1.0f + __expf(-v0.w));
    r.x = gx * m.x + (1.0f - gx) * v0.x;
    r.y = gy * m.y + (1.0f - gy) * v0.y;
    r.z = gz * m.z + (1.0f - gz) * v0.z;
    r.w = gw * m.w + (1.0f - gw) * v0.w;

    __builtin_nontemporal_store(r, reinterpret_cast<f32x4*>(out + base) + lane);
}

extern "C" void kernel_launch(void* const* d_in, const int* in_sizes, int n_in,
                              void* d_out, int out_size, void* d_ws, size_t ws_size,
                              hipStream_t stream)
{
    const float* x   = (const float*)d_in[0];
    const int*   idx = (const int*)d_in[1];
    const int n_idx  = in_sizes[1];
    float* out = (float*)d_out;

    const int n_rows = in_sizes[0] / H_LEN;   // B*S = 65536
    const int nwg = n_rows / ROWS_PER_BLOCK;  // 8192
    ngram_min_pool<<<nwg, NTHREADS, 0, stream>>>(x, idx, n_idx, out, nwg);
}